// Round 11
// baseline (152.241 us; speedup 1.0000x reference)
//
#include <hip/hip_runtime.h>
#include <math.h>

#define N 1024
#define M 128

typedef unsigned short us16;

__device__ __forceinline__ us16 f2bf(float f) {
  unsigned int u = __float_as_uint(f);
  unsigned int r = u + 0x7FFFu + ((u >> 16) & 1u);   // RNE
  return (us16)(r >> 16);
}
__device__ __forceinline__ float bf2f(us16 u) {
  return __uint_as_float(((unsigned int)u) << 16);
}

// ---------------- block reductions (256-thread blocks: edge only) ----------------
__device__ __forceinline__ float blk_max(float v, float* red, int t) {
#pragma unroll
  for (int o = 32; o; o >>= 1) v = fmaxf(v, __shfl_xor(v, o));
  __syncthreads();
  if ((t & 63) == 0) red[t >> 6] = v;
  __syncthreads();
  return fmaxf(fmaxf(red[0], red[1]), fmaxf(red[2], red[3]));
}
__device__ __forceinline__ float blk_sum(float v, float* red, int t) {
#pragma unroll
  for (int o = 32; o; o >>= 1) v += __shfl_xor(v, o);
  __syncthreads();
  if ((t & 63) == 0) red[t >> 6] = v;
  __syncthreads();
  return red[0] + red[1] + red[2] + red[3];
}

// ================= edge (direct D columns) + all prep work, one launch =================
__global__ __launch_bounds__(256) void k_edge_prep(
    const float* __restrict__ D, const float* __restrict__ dd,
    const float* __restrict__ W1, const float* __restrict__ W2,
    us16* __restrict__ PT1bf, us16* __restrict__ PT2bf,
    float* __restrict__ wd1, float* __restrict__ wd2,
    const float* __restrict__ W3A1, const float* __restrict__ W3A2,
    const float* __restrict__ W3B, const float* __restrict__ W4B,
    float* __restrict__ W3A1T, float* __restrict__ W3A2T,
    float* __restrict__ W3BT, float* __restrict__ W4BT,
    const float* __restrict__ mu0A1, const float* __restrict__ mu0A2,
    const float* __restrict__ mu0B,
    const float* __restrict__ W5, const float* __restrict__ W6,
    float* __restrict__ s1, float* __restrict__ s2,
    us16* __restrict__ muA1_0, us16* __restrict__ muA2_0, us16* __restrict__ muB_0,
    float* __restrict__ gsum, unsigned int* __restrict__ gcnt) {
  __shared__ float4 wp[128];
  __shared__ float red[4];
  int bx = blockIdx.x, t = threadIdx.x;
  if (bx < 1024) {
    // ---- edge scores + dual softmax + wd for target v = bx ----
    // G_scaled = G_raw/1000 exactly (relu positively homogeneous) -> one MLP, two temps.
    int v = bx;
    if (t < 128) {
      float4 p;
      p.x = W2[t * 3 + 0]; p.y = W2[t * 3 + 1]; p.z = W2[t * 3 + 2]; p.w = W1[t];
      wp[t] = p;
    }
    __syncthreads();
    float yv = dd[v];
    float x[4], z[4], g[4] = {0.f, 0.f, 0.f, 0.f};
#pragma unroll
    for (int i = 0; i < 4; i++)
      x[i] = D[(size_t)(t * 4 + i) * N + v];   // column read (hidden by MLP loop)
    float4 zv = *(const float4*)&dd[t * 4];
    z[0] = zv.x; z[1] = zv.y; z[2] = zv.z; z[3] = zv.w;
#pragma unroll 2
    for (int k = 0; k < 128; k++) {
      float4 wk = wp[k];
      float cv = yv * wk.z;
#pragma unroll
      for (int i = 0; i < 4; i++) {
        float h = fmaf(x[i], wk.x, fmaf(z[i], wk.y, cv));
        g[i] = fmaf(fmaxf(h, 0.f), wk.w, g[i]);
      }
    }
#pragma unroll
    for (int i = 0; i < 4; i++)
      if (t * 4 + i == v) g[i] = -INFINITY;
    float m = fmaxf(fmaxf(g[0], g[1]), fmaxf(g[2], g[3]));
    m = blk_max(m, red, t);
    float er[4], es[4], sr = 0.f, ss = 0.f;
#pragma unroll
    for (int i = 0; i < 4; i++) {
      er[i] = expf((g[i] - m) * 0.1f);     // raw: /TAU
      es[i] = expf((g[i] - m) * 1e-4f);    // scaled: /(1000*TAU)
      sr += er[i]; ss += es[i];
    }
    sr = blk_sum(sr, red, t);
    ss = blk_sum(ss, red, t);
    float ir = 1.f / sr, is = 1.f / ss;
    float ps0 = es[0] * is, ps1 = es[1] * is, ps2 = es[2] * is, ps3 = es[3] * is;
    float pr0 = er[0] * ir, pr1 = er[1] * ir, pr2 = er[2] * ir, pr3 = er[3] * ir;
    ushort4 p1, p2;
    p1.x = f2bf(ps0); p1.y = f2bf(ps1); p1.z = f2bf(ps2); p1.w = f2bf(ps3);
    p2.x = f2bf(pr0); p2.y = f2bf(pr1); p2.z = f2bf(pr2); p2.w = f2bf(pr3);
    *(ushort4*)(PT1bf + (size_t)v * N + t * 4) = p1;
    *(ushort4*)(PT2bf + (size_t)v * N + t * 4) = p2;
    float a1 = ps0 * x[0] + ps1 * x[1] + ps2 * x[2] + ps3 * x[3];
    float a2 = pr0 * x[0] + pr1 * x[1] + pr2 * x[2] + pr3 * x[3];
    a1 = blk_sum(a1, red, t);
    a2 = blk_sum(a2, red, t);
    if (t == 0) { wd1[v] = a1; wd2[v] = a2; }
  } else if (bx < 1345) {                // weight transposes (f32): out[c*128+r] = in[r*cols+c]
    int idx = (bx - 1024) * 256 + t;
    const float* in = nullptr; float* op = nullptr; int cols = 0, o = 0;
    if (idx < 16512)      { in = W3A1; op = W3A1T; cols = 129; o = idx; }
    else if (idx < 33024) { in = W3A2; op = W3A2T; cols = 129; o = idx - 16512; }
    else if (idx < 49408) { in = W3B;  op = W3BT;  cols = 128; o = idx - 33024; }
    else if (idx < 82176) { in = W4B;  op = W4BT;  cols = 256; o = idx - 49408; }
    if (in) { int r = o & 127, c = o >> 7; op[o] = in[r * cols + c]; }
  } else if (bx < 1473) {                // s0 = mu0 . Wg (raw dot)
    int idx = (bx - 1345) * 256 + t;     // < 32768
    int row = idx >> 4, l16 = idx & 15;
    int chain = row >> 10, r = row & 1023;
    const float* mu0 = chain ? mu0A2 : mu0A1;
    const float* Wg = chain ? W6 : W5;
    float* sb = chain ? s2 : s1;
    const float* mp = mu0 + (size_t)r * M + l16 * 8;
    float4 a0 = *(const float4*)mp, a1 = *(const float4*)(mp + 4);
    float4 g0 = *(const float4*)(Wg + l16 * 8), g1 = *(const float4*)(Wg + l16 * 8 + 4);
    float sp = a0.x * g0.x + a0.y * g0.y + a0.z * g0.z + a0.w * g0.w
             + a1.x * g1.x + a1.y * g1.y + a1.z * g1.z + a1.w * g1.w;
#pragma unroll
    for (int o = 8; o; o >>= 1) sp += __shfl_xor(sp, o);
    if (l16 == 0) sb[r] = sp;
  } else if (bx < 1857) {                // mu0 -> bf16 row-major
    int idx = (bx - 1473) * 256 + t;     // < 98304
    int mat = idx >> 15, o4 = idx & 32767;
    const float* src = mat == 0 ? mu0A1 : (mat == 1 ? mu0A2 : mu0B);
    us16* dst = mat == 0 ? muA1_0 : (mat == 1 ? muA2_0 : muB_0);
    float4 v = *(const float4*)(src + (size_t)o4 * 4);
    ushort4 p;
    p.x = f2bf(v.x); p.y = f2bf(v.y); p.z = f2bf(v.z); p.w = f2bf(v.w);
    *(ushort4*)(dst + (size_t)o4 * 4) = p;
  } else {
    if (t == 0) { *gsum = 0.f; *gcnt = 0u; }
  }
}

// ---------------- GEMM core (1024 threads): 4 rows/block, full K, 32-way K-split ----------------
// smem: As[4096] f32 (A rows -> Cred[4][128]); CsP[8192] (16-slice partials after pair-merge)
__device__ __forceinline__ void gemm4_bf(const us16* __restrict__ PTbf,
                                         const us16* __restrict__ curbf,
                                         float* __restrict__ As, float* __restrict__ CsP,
                                         int r0, int t) {
  {
    int row = t >> 8, c4 = t & 255;     // one float4 per thread
    ushort4 a = *(const ushort4*)(PTbf + (size_t)(r0 + row) * N + c4 * 4);
    float4 f;
    f.x = bf2f(a.x); f.y = bf2f(a.y); f.z = bf2f(a.z); f.w = bf2f(a.w);
    *(float4*)&As[row * 1024 + c4 * 4] = f;
  }
  __syncthreads();
  const int kc = t >> 5;        // 0..31: K-slice of 32
  const int cg = t & 31;        // col group *4
  const int u0 = kc * 32;
  float4 acc0 = {0,0,0,0}, acc1 = {0,0,0,0}, acc2 = {0,0,0,0}, acc3 = {0,0,0,0};
  const us16* mub = curbf + (size_t)u0 * M + cg * 4;
  const float* a0p = As + u0;
  const float* a1p = As + 1024 + u0;
  const float* a2p = As + 2048 + u0;
  const float* a3p = As + 3072 + u0;
#pragma unroll
  for (int uu = 0; uu < 32; uu += 4) {
    float4 a0 = *(const float4*)&a0p[uu];
    float4 a1 = *(const float4*)&a1p[uu];
    float4 a2 = *(const float4*)&a2p[uu];
    float4 a3 = *(const float4*)&a3p[uu];
    ushort4 v0 = *(const ushort4*)&mub[(size_t)(uu + 0) * M];
    ushort4 v1 = *(const ushort4*)&mub[(size_t)(uu + 1) * M];
    ushort4 v2 = *(const ushort4*)&mub[(size_t)(uu + 2) * M];
    ushort4 v3 = *(const ushort4*)&mub[(size_t)(uu + 3) * M];
    float4 b0 = {bf2f(v0.x), bf2f(v0.y), bf2f(v0.z), bf2f(v0.w)};
    float4 b1 = {bf2f(v1.x), bf2f(v1.y), bf2f(v1.z), bf2f(v1.w)};
    float4 b2 = {bf2f(v2.x), bf2f(v2.y), bf2f(v2.z), bf2f(v2.w)};
    float4 b3 = {bf2f(v3.x), bf2f(v3.y), bf2f(v3.z), bf2f(v3.w)};
#define FMA4(ACC, AV) \
    ACC.x = fmaf(AV.x, b0.x, ACC.x); ACC.y = fmaf(AV.x, b0.y, ACC.y); \
    ACC.z = fmaf(AV.x, b0.z, ACC.z); ACC.w = fmaf(AV.x, b0.w, ACC.w); \
    ACC.x = fmaf(AV.y, b1.x, ACC.x); ACC.y = fmaf(AV.y, b1.y, ACC.y); \
    ACC.z = fmaf(AV.y, b1.z, ACC.z); ACC.w = fmaf(AV.y, b1.w, ACC.w); \
    ACC.x = fmaf(AV.z, b2.x, ACC.x); ACC.y = fmaf(AV.z, b2.y, ACC.y); \
    ACC.z = fmaf(AV.z, b2.z, ACC.z); ACC.w = fmaf(AV.z, b2.w, ACC.w); \
    ACC.x = fmaf(AV.w, b3.x, ACC.x); ACC.y = fmaf(AV.w, b3.y, ACC.y); \
    ACC.z = fmaf(AV.w, b3.z, ACC.z); ACC.w = fmaf(AV.w, b3.w, ACC.w);
    FMA4(acc0, a0) FMA4(acc1, a1) FMA4(acc2, a2) FMA4(acc3, a3)
#undef FMA4
  }
  // paired two-pass reduction: slices 16..31 store, slices 0..15 add in place
  float* cp = CsP + (kc & 15) * 512 + cg * 4;
  if (kc >= 16) {
    *(float4*)&cp[0]   = acc0;
    *(float4*)&cp[128] = acc1;
    *(float4*)&cp[256] = acc2;
    *(float4*)&cp[384] = acc3;
  }
  __syncthreads();
  if (kc < 16) {
    float4 p0 = *(float4*)&cp[0],   p1 = *(float4*)&cp[128];
    float4 p2 = *(float4*)&cp[256], p3 = *(float4*)&cp[384];
    p0.x += acc0.x; p0.y += acc0.y; p0.z += acc0.z; p0.w += acc0.w;
    p1.x += acc1.x; p1.y += acc1.y; p1.z += acc1.z; p1.w += acc1.w;
    p2.x += acc2.x; p2.y += acc2.y; p2.z += acc2.z; p2.w += acc2.w;
    p3.x += acc3.x; p3.y += acc3.y; p3.z += acc3.z; p3.w += acc3.w;
    *(float4*)&cp[0]   = p0;
    *(float4*)&cp[128] = p1;
    *(float4*)&cp[256] = p2;
    *(float4*)&cp[384] = p3;
  }
  __syncthreads();
  if (t < 512) {
    float s = 0.f;
#pragma unroll
    for (int s16 = 0; s16 < 16; s16++) s += CsP[s16 * 512 + t];
    As[t] = s;                     // Cred[4][128]
  }
  __syncthreads();
}

// epilogue matmul (1 row/thread): acc = Cred_row @ W3T-column (wcol pre-offset)
__device__ __forceinline__ float epi_mm1(const float* __restrict__ Cred,
                                         const float* __restrict__ wcol, int ra) {
  float acc = 0.f;
#pragma unroll 4
  for (int m = 0; m < 128; m += 4) {
    float4 c0 = *(const float4*)&Cred[ra * 128 + m];
    acc = fmaf(c0.x, wcol[(m + 0) * 128],
          fmaf(c0.y, wcol[(m + 1) * 128],
          fmaf(c0.z, wcol[(m + 2) * 128],
          fmaf(c0.w, wcol[(m + 3) * 128], acc))));
  }
  return acc;
}

// ================= fused A-iteration (it 0..2; z=0: A1, z=1: A2, z=2: B0 GEMM at it0) =================
__global__ __launch_bounds__(1024, 1) void k_iterA(
    const us16* __restrict__ PT1bf, const us16* __restrict__ PT2bf,
    const us16* __restrict__ cur1, const us16* __restrict__ cur2,
    const us16* __restrict__ curB0,
    us16* __restrict__ nxt1, us16* __restrict__ nxt2, float* __restrict__ CB0f,
    float* __restrict__ s1buf, float* __restrict__ s2buf,
    const float* __restrict__ wd1, const float* __restrict__ wd2,
    const float* __restrict__ dr, const float* __restrict__ ddep,
    const float* __restrict__ W3A1T, const float* __restrict__ W3A2T,
    const float* __restrict__ W3BT,
    const float* __restrict__ W4A1, const float* __restrict__ W4A2,
    const float* __restrict__ W5, const float* __restrict__ W6) {
  __shared__ float smem[12288];      // As[4096] + CsP[8192] = 48 KB
  float* As = smem;
  float* CsP = smem + 4096;
  const int z = blockIdx.z;
  const int t = threadIdx.x, r0 = blockIdx.x * 4;
  const us16* PT = (z == 1) ? PT2bf : PT1bf;
  const us16* cur = (z == 0) ? cur1 : (z == 1) ? cur2 : curB0;

  gemm4_bf(PT, cur, As, CsP, r0, t);

  const float* W3T = (z == 0) ? W3A1T : (z == 1) ? W3A2T : W3BT;
  int col = t & 127, ra = (t >> 7) & 3;
  int rA = r0 + ra;
  if (z == 2) {                       // B0 GEMM: store raw C (pre-bias, pre-relu)
    if (t < 512) CB0f[(size_t)rA * M + col] = epi_mm1(As, W3T + col, ra);
    return;
  }
  float* sbuf = z ? s2buf : s1buf;
  const float* wdv = z ? wd2 : wd1;
  const float* dist = z ? ddep : dr;
  const float* W4c = z ? W4A2 : W4A1;
  const float* Wg = z ? W6 : W5;
  us16* nxt = z ? nxt2 : nxt1;
  float o0 = 0.f;
  if (t < 512) {
    float acc = epi_mm1(As, W3T + 128 + col, ra);
    float w30 = W3T[col], w4 = W4c[col];
    float sv = wdv[rA] * fmaxf(sbuf[rA], 0.f);
    o0 = fmaxf(fmaf(sv, w30, fmaf(dist[rA], w4, acc)), 0.f);
    nxt[(size_t)rA * M + col] = f2bf(o0);
  }
  // producer-side s-dot for next iteration's epilogue
  __syncthreads();
  if (t < 512) CsP[ra * 128 + col] = o0;
  __syncthreads();
  if (t < 64) {
    int row = t >> 4, l16 = t & 15;
    const float* cr = &CsP[row * 128 + l16 * 8];
    float4 x0 = *(const float4*)cr, x1 = *(const float4*)(cr + 4);
    float4 g0 = *(const float4*)(Wg + l16 * 8), g1 = *(const float4*)(Wg + l16 * 8 + 4);
    float sp = x0.x * g0.x + x0.y * g0.y + x0.z * g0.z + x0.w * g0.w
             + x1.x * g1.x + x1.y * g1.y + x1.z * g1.z + x1.w * g1.w;
#pragma unroll
    for (int o = 8; o; o >>= 1) sp += __shfl_xor(sp, o);
    if (l16 == 0) sbuf[r0 + row] = sp;
  }
}

// ================= A-it3 fused: both chains + bias + muB1 (bmerge folded in) =================
__global__ __launch_bounds__(1024, 1) void k_iterA3(
    const us16* __restrict__ PT1bf, const us16* __restrict__ PT2bf,
    const us16* __restrict__ curA1, const us16* __restrict__ curA2,
    us16* __restrict__ nxtA1, us16* __restrict__ nxtA2,
    const float* __restrict__ s1buf, const float* __restrict__ s2buf,
    const float* __restrict__ wd1, const float* __restrict__ wd2,
    const float* __restrict__ dr, const float* __restrict__ ddep,
    const float* __restrict__ W3A1T, const float* __restrict__ W3A2T,
    const float* __restrict__ W4A1, const float* __restrict__ W4A2,
    const float* __restrict__ W4BT, const float* __restrict__ CB0f,
    float* __restrict__ biasb, us16* __restrict__ muB1) {
  __shared__ float smem[12288 + 512];
  float* As = smem;
  float* CsP = smem + 4096;
  float* st1 = smem + 12288;          // chain-1 new mu f32 [4][128]
  const int t = threadIdx.x, r0 = blockIdx.x * 4;
  int col = t & 127, ra = (t >> 7) & 3;
  int rA = r0 + ra;

  // ---- chain 1 (A1) ----
  gemm4_bf(PT1bf, curA1, As, CsP, r0, t);
  if (t < 512) {
    float acc = epi_mm1(As, W3A1T + 128 + col, ra);
    float w30 = W3A1T[col], w4 = W4A1[col];
    float sv = wd1[rA] * fmaxf(s1buf[rA], 0.f);
    float o0 = fmaxf(fmaf(sv, w30, fmaf(dr[rA], w4, acc)), 0.f);
    nxtA1[(size_t)rA * M + col] = f2bf(o0);
    st1[ra * 128 + col] = o0;
  }
  __syncthreads();   // epi reads of As done before chain-2 staging overwrites

  // ---- chain 2 (A2) ----
  gemm4_bf(PT2bf, curA2, As, CsP, r0, t);
  if (t < 512) {
    float acc = epi_mm1(As, W3A2T + 128 + col, ra);
    float w30 = W3A2T[col], w4 = W4A2[col];
    float sv = wd2[rA] * fmaxf(s2buf[rA], 0.f);
    float o0 = fmaxf(fmaf(sv, w30, fmaf(ddep[rA], w4, acc)), 0.f);
    nxtA2[(size_t)rA * M + col] = f2bf(o0);
    CsP[ra * 128 + col] = o0;          // stash chain-2 (CsP free after gemm4)
  }
  __syncthreads();

  // ---- bias = [A1new, A2new] @ W4B.T ; muB1 = relu(CB0 + bias) (block-local rows) ----
  if (t < 512) {
    float b0 = 0.f;
#pragma unroll 4
    for (int c = 0; c < 128; c += 4) {
      float4 s0 = *(const float4*)&st1[ra * 128 + c];
      float w0 = W4BT[(c + 0) * 128 + col], w1 = W4BT[(c + 1) * 128 + col];
      float w2 = W4BT[(c + 2) * 128 + col], w3 = W4BT[(c + 3) * 128 + col];
      b0 = fmaf(s0.x, w0, fmaf(s0.y, w1, fmaf(s0.z, w2, fmaf(s0.w, w3, b0))));
    }
#pragma unroll 4
    for (int c = 0; c < 128; c += 4) {
      float4 s0 = *(const float4*)&CsP[ra * 128 + c];
      float w0 = W4BT[(c + 128) * 128 + col], w1 = W4BT[(c + 129) * 128 + col];
      float w2 = W4BT[(c + 130) * 128 + col], w3 = W4BT[(c + 131) * 128 + col];
      b0 = fmaf(s0.x, w0, fmaf(s0.y, w1, fmaf(s0.z, w2, fmaf(s0.w, w3, b0))));
    }
    biasb[(size_t)rA * M + col] = b0;
    muB1[(size_t)rA * M + col] = f2bf(fmaxf(CB0f[(size_t)rA * M + col] + b0, 0.f));
  }
}

// ================= fused B-iteration (B1..B3) =================
__global__ __launch_bounds__(1024, 1) void k_iterB(
    const us16* __restrict__ PT1bf, const us16* __restrict__ curbf,
    us16* __restrict__ nxtbf,
    const float* __restrict__ W3BT, const float* __restrict__ biasb,
    const float* __restrict__ W7, float* __restrict__ gsum,
    unsigned int* __restrict__ gcnt, float* __restrict__ out, int last) {
  __shared__ float smem[12288];
  __shared__ float redf[16];
  float* As = smem;
  float* CsP = smem + 4096;
  int t = threadIdx.x, r0 = blockIdx.x * 4;
  gemm4_bf(PT1bf, curbf, As, CsP, r0, t);
  int col = t & 127, ra = (t >> 7) & 3;
  int rA = r0 + ra;
  float o0 = 0.f;
  if (t < 512) {
    float acc = epi_mm1(As, W3BT + col, ra);
    o0 = fmaxf(acc + biasb[(size_t)rA * M + col], 0.f);
  }
  if (!last) {
    if (t < 512) nxtbf[(size_t)rA * M + col] = f2bf(o0);
  } else {
    float s = (t < 512) ? o0 * W7[col] : 0.f;
#pragma unroll
    for (int off = 32; off; off >>= 1) s += __shfl_xor(s, off);
    if ((t & 63) == 0) redf[t >> 6] = s;
    __syncthreads();
    if (t == 0) {
      float bs = 0.f;
#pragma unroll
      for (int i = 0; i < 16; i++) bs += redf[i];
      atomicAdd(gsum, bs);
      __threadfence();
      unsigned int old = atomicAdd(gcnt, 1u);
      if (old == 255u) {
        float tot = atomicAdd(gsum, 0.f);
        out[0] = fmaxf(tot, 0.f);
      }
    }
  }
}

extern "C" void kernel_launch(void* const* d_in, const int* in_sizes, int n_in,
                              void* d_out, int out_size, void* d_ws, size_t ws_size,
                              hipStream_t stream) {
  (void)in_sizes; (void)n_in; (void)out_size; (void)ws_size;
  const float* D     = (const float*)d_in[0];
  const float* dd    = (const float*)d_in[1];
  const float* dr    = (const float*)d_in[2];
  const float* ddep  = (const float*)d_in[3];
  const float* mu0A1 = (const float*)d_in[4];
  const float* mu0A2 = (const float*)d_in[5];
  const float* mu0B  = (const float*)d_in[6];
  const float* W1    = (const float*)d_in[7];
  const float* W2    = (const float*)d_in[8];
  const float* W3A1  = (const float*)d_in[9];
  const float* W3A2  = (const float*)d_in[10];
  const float* W4A1  = (const float*)d_in[11];
  const float* W4A2  = (const float*)d_in[12];
  const float* W3B   = (const float*)d_in[13];
  const float* W4B   = (const float*)d_in[14];
  const float* W5    = (const float*)d_in[15];
  const float* W6    = (const float*)d_in[16];
  const float* W7    = (const float*)d_in[17];

  float* wsf = (float*)d_ws;
  size_t o = 0;
  auto alloc = [&](size_t n) { float* p = wsf + o; o += n; return p; };
  us16* PT1bf   = (us16*)alloc((size_t)N * N / 2);
  us16* PT2bf   = (us16*)alloc((size_t)N * N / 2);
  float* W3A1T  = alloc(129 * 128);
  float* W3A2T  = alloc(129 * 128);
  float* W3BT   = alloc(128 * 128);
  float* W4BT   = alloc(256 * 128);
  float* s1     = alloc(N);
  float* s2     = alloc(N);
  float* wd1    = alloc(N);
  float* wd2    = alloc(N);
  us16* muA1_0  = (us16*)alloc((size_t)N * M / 2);
  us16* muA1_a  = (us16*)alloc((size_t)N * M / 2);
  us16* muA1_b  = (us16*)alloc((size_t)N * M / 2);
  us16* muA2_0  = (us16*)alloc((size_t)N * M / 2);
  us16* muA2_a  = (us16*)alloc((size_t)N * M / 2);
  us16* muA2_b  = (us16*)alloc((size_t)N * M / 2);
  us16* muB_0   = (us16*)alloc((size_t)N * M / 2);
  us16* muB_a   = (us16*)alloc((size_t)N * M / 2);
  us16* muB_b   = (us16*)alloc((size_t)N * M / 2);
  float* CB0f   = alloc((size_t)N * M);
  float* biasb  = alloc((size_t)N * M);
  float* gsum   = alloc(1);
  unsigned int* gcnt = (unsigned int*)alloc(1);

  // Stage 1: edge (direct-D) + all prep work in one launch
  k_edge_prep<<<1858, 256, 0, stream>>>(D, dd, W1, W2, PT1bf, PT2bf, wd1, wd2,
                                        W3A1, W3A2, W3B, W4B,
                                        W3A1T, W3A2T, W3BT, W4BT,
                                        mu0A1, mu0A2, mu0B, W5, W6, s1, s2,
                                        muA1_0, muA2_0, muB_0, gsum, gcnt);

  // Stages 2-4: A iterations 0..2 (it0 carries B0 GEMM as z=2)
  const us16* c1 = muA1_0;
  const us16* c2 = muA2_0;
  us16* b1[2] = {muA1_a, muA1_b};
  us16* b2[2] = {muA2_a, muA2_b};
  for (int it = 0; it < 3; it++) {
    dim3 grid(256, 1, it == 0 ? 3 : 2);
    k_iterA<<<grid, 1024, 0, stream>>>(PT1bf, PT2bf, c1, c2, muB_0,
        b1[it & 1], b2[it & 1], CB0f, s1, s2, wd1, wd2, dr, ddep,
        W3A1T, W3A2T, W3BT, W4A1, W4A2, W5, W6);
    c1 = b1[it & 1];
    c2 = b2[it & 1];
  }

  // Stage 5: A it3 + bias + muB1 (bmerge fused)
  k_iterA3<<<256, 1024, 0, stream>>>(PT1bf, PT2bf, c1, c2,
      muA1_b, muA2_b, s1, s2, wd1, wd2, dr, ddep,
      W3A1T, W3A2T, W4A1, W4A2, W4BT, CB0f, biasb, muB_a);

  // Stages 6-8: B1..B3
  const us16* cB = muB_a;
  us16* bB[2] = {muB_b, muB_a};
  for (int i = 0; i < 3; i++) {
    k_iterB<<<256, 1024, 0, stream>>>(PT1bf, cB, bB[i & 1],
        W3BT, biasb, W7, gsum, gcnt, (float*)d_out, i == 2 ? 1 : 0);
    cB = bB[i & 1];
  }
}

// Round 12
// 133.054 us; speedup vs baseline: 1.1442x; 1.1442x over previous
//
#include <hip/hip_runtime.h>
#include <math.h>

#define N 1024
#define M 128

typedef unsigned short us16;

__device__ __forceinline__ us16 f2bf(float f) {
  unsigned int u = __float_as_uint(f);
  unsigned int r = u + 0x7FFFu + ((u >> 16) & 1u);   // RNE
  return (us16)(r >> 16);
}
__device__ __forceinline__ float bf2f(us16 u) {
  return __uint_as_float(((unsigned int)u) << 16);
}

// ---------------- block reductions (256-thread blocks: edge only) ----------------
__device__ __forceinline__ float blk_max(float v, float* red, int t) {
#pragma unroll
  for (int o = 32; o; o >>= 1) v = fmaxf(v, __shfl_xor(v, o));
  __syncthreads();
  if ((t & 63) == 0) red[t >> 6] = v;
  __syncthreads();
  return fmaxf(fmaxf(red[0], red[1]), fmaxf(red[2], red[3]));
}
__device__ __forceinline__ float blk_sum(float v, float* red, int t) {
#pragma unroll
  for (int o = 32; o; o >>= 1) v += __shfl_xor(v, o);
  __syncthreads();
  if ((t & 63) == 0) red[t >> 6] = v;
  __syncthreads();
  return red[0] + red[1] + red[2] + red[3];
}

// ================= edge (direct D columns) + all prep work, one launch =================
__global__ __launch_bounds__(256) void k_edge_prep(
    const float* __restrict__ D, const float* __restrict__ dd,
    const float* __restrict__ W1, const float* __restrict__ W2,
    us16* __restrict__ PT1bf, us16* __restrict__ PT2bf,
    float* __restrict__ wd1, float* __restrict__ wd2,
    const float* __restrict__ W3A1, const float* __restrict__ W3A2,
    const float* __restrict__ W3B, const float* __restrict__ W4B,
    float* __restrict__ W3A1T, float* __restrict__ W3A2T,
    float* __restrict__ W3BT, float* __restrict__ W4BT,
    const float* __restrict__ mu0A1, const float* __restrict__ mu0A2,
    const float* __restrict__ mu0B,
    const float* __restrict__ W5, const float* __restrict__ W6,
    float* __restrict__ s1, float* __restrict__ s2,
    us16* __restrict__ muA1_0, us16* __restrict__ muA2_0, us16* __restrict__ muB_0,
    float* __restrict__ gsum, unsigned int* __restrict__ gcnt) {
  __shared__ float4 wp[128];
  __shared__ float red[4];
  int bx = blockIdx.x, t = threadIdx.x;
  if (bx < 1024) {
    // ---- edge scores + dual softmax + wd for target v = bx ----
    // G_scaled = G_raw/1000 exactly (relu positively homogeneous) -> one MLP, two temps.
    int v = bx;
    if (t < 128) {
      float4 p;
      p.x = W2[t * 3 + 0]; p.y = W2[t * 3 + 1]; p.z = W2[t * 3 + 2]; p.w = W1[t];
      wp[t] = p;
    }
    __syncthreads();
    float yv = dd[v];
    float x[4], z[4], g[4] = {0.f, 0.f, 0.f, 0.f};
#pragma unroll
    for (int i = 0; i < 4; i++)
      x[i] = D[(size_t)(t * 4 + i) * N + v];   // column read (hidden by MLP loop)
    float4 zv = *(const float4*)&dd[t * 4];
    z[0] = zv.x; z[1] = zv.y; z[2] = zv.z; z[3] = zv.w;
#pragma unroll 2
    for (int k = 0; k < 128; k++) {
      float4 wk = wp[k];
      float cv = yv * wk.z;
#pragma unroll
      for (int i = 0; i < 4; i++) {
        float h = fmaf(x[i], wk.x, fmaf(z[i], wk.y, cv));
        g[i] = fmaf(fmaxf(h, 0.f), wk.w, g[i]);
      }
    }
#pragma unroll
    for (int i = 0; i < 4; i++)
      if (t * 4 + i == v) g[i] = -INFINITY;
    float m = fmaxf(fmaxf(g[0], g[1]), fmaxf(g[2], g[3]));
    m = blk_max(m, red, t);
    float er[4], es[4], sr = 0.f, ss = 0.f;
#pragma unroll
    for (int i = 0; i < 4; i++) {
      er[i] = expf((g[i] - m) * 0.1f);     // raw: /TAU
      es[i] = expf((g[i] - m) * 1e-4f);    // scaled: /(1000*TAU)
      sr += er[i]; ss += es[i];
    }
    sr = blk_sum(sr, red, t);
    ss = blk_sum(ss, red, t);
    float ir = 1.f / sr, is = 1.f / ss;
    float ps0 = es[0] * is, ps1 = es[1] * is, ps2 = es[2] * is, ps3 = es[3] * is;
    float pr0 = er[0] * ir, pr1 = er[1] * ir, pr2 = er[2] * ir, pr3 = er[3] * ir;
    ushort4 p1, p2;
    p1.x = f2bf(ps0); p1.y = f2bf(ps1); p1.z = f2bf(ps2); p1.w = f2bf(ps3);
    p2.x = f2bf(pr0); p2.y = f2bf(pr1); p2.z = f2bf(pr2); p2.w = f2bf(pr3);
    *(ushort4*)(PT1bf + (size_t)v * N + t * 4) = p1;
    *(ushort4*)(PT2bf + (size_t)v * N + t * 4) = p2;
    float a1 = ps0 * x[0] + ps1 * x[1] + ps2 * x[2] + ps3 * x[3];
    float a2 = pr0 * x[0] + pr1 * x[1] + pr2 * x[2] + pr3 * x[3];
    a1 = blk_sum(a1, red, t);
    a2 = blk_sum(a2, red, t);
    if (t == 0) { wd1[v] = a1; wd2[v] = a2; }
  } else if (bx < 1345) {                // weight transposes (f32): out[c*128+r] = in[r*cols+c]
    int idx = (bx - 1024) * 256 + t;
    const float* in = nullptr; float* op = nullptr; int cols = 0, o = 0;
    if (idx < 16512)      { in = W3A1; op = W3A1T; cols = 129; o = idx; }
    else if (idx < 33024) { in = W3A2; op = W3A2T; cols = 129; o = idx - 16512; }
    else if (idx < 49408) { in = W3B;  op = W3BT;  cols = 128; o = idx - 33024; }
    else if (idx < 82176) { in = W4B;  op = W4BT;  cols = 256; o = idx - 49408; }
    if (in) { int r = o & 127, c = o >> 7; op[o] = in[r * cols + c]; }
  } else if (bx < 1473) {                // s0 = mu0 . Wg (raw dot)
    int idx = (bx - 1345) * 256 + t;     // < 32768
    int row = idx >> 4, l16 = idx & 15;
    int chain = row >> 10, r = row & 1023;
    const float* mu0 = chain ? mu0A2 : mu0A1;
    const float* Wg = chain ? W6 : W5;
    float* sb = chain ? s2 : s1;
    const float* mp = mu0 + (size_t)r * M + l16 * 8;
    float4 a0 = *(const float4*)mp, a1 = *(const float4*)(mp + 4);
    float4 g0 = *(const float4*)(Wg + l16 * 8), g1 = *(const float4*)(Wg + l16 * 8 + 4);
    float sp = a0.x * g0.x + a0.y * g0.y + a0.z * g0.z + a0.w * g0.w
             + a1.x * g1.x + a1.y * g1.y + a1.z * g1.z + a1.w * g1.w;
#pragma unroll
    for (int o = 8; o; o >>= 1) sp += __shfl_xor(sp, o);
    if (l16 == 0) sb[r] = sp;
  } else if (bx < 1857) {                // mu0 -> bf16 row-major
    int idx = (bx - 1473) * 256 + t;     // < 98304
    int mat = idx >> 15, o4 = idx & 32767;
    const float* src = mat == 0 ? mu0A1 : (mat == 1 ? mu0A2 : mu0B);
    us16* dst = mat == 0 ? muA1_0 : (mat == 1 ? muA2_0 : muB_0);
    float4 v = *(const float4*)(src + (size_t)o4 * 4);
    ushort4 p;
    p.x = f2bf(v.x); p.y = f2bf(v.y); p.z = f2bf(v.z); p.w = f2bf(v.w);
    *(ushort4*)(dst + (size_t)o4 * 4) = p;
  } else {
    if (t == 0) { *gsum = 0.f; *gcnt = 0u; }
  }
}

// ---------------- GEMM core (512 threads): 4 rows/block, full K, 16-way K-split ----------------
// smem: As[4096] f32 (A rows -> Cred[4][128]); CsP[8192] (partials; free afterwards)
__device__ __forceinline__ void gemm4_bf(const us16* __restrict__ PTbf,
                                         const us16* __restrict__ curbf,
                                         float* __restrict__ As, float* __restrict__ CsP,
                                         int r0, int t) {
#pragma unroll
  for (int i = 0; i < 2; i++) {
    int idx = t + i * 512;
    int row = idx >> 8, c4 = idx & 255;
    ushort4 a = *(const ushort4*)(PTbf + (size_t)(r0 + row) * N + c4 * 4);
    float4 f;
    f.x = bf2f(a.x); f.y = bf2f(a.y); f.z = bf2f(a.z); f.w = bf2f(a.w);
    *(float4*)&As[row * 1024 + c4 * 4] = f;
  }
  __syncthreads();
  const int kc = t >> 5;        // 0..15: K-slice of 64
  const int cg = t & 31;        // col group *4
  const int u0 = kc * 64;
  float4 acc0 = {0,0,0,0}, acc1 = {0,0,0,0}, acc2 = {0,0,0,0}, acc3 = {0,0,0,0};
  const us16* mub = curbf + (size_t)u0 * M + cg * 4;
  const float* a0p = As + u0;
  const float* a1p = As + 1024 + u0;
  const float* a2p = As + 2048 + u0;
  const float* a3p = As + 3072 + u0;
#pragma unroll 2
  for (int uu = 0; uu < 64; uu += 4) {
    float4 a0 = *(const float4*)&a0p[uu];
    float4 a1 = *(const float4*)&a1p[uu];
    float4 a2 = *(const float4*)&a2p[uu];
    float4 a3 = *(const float4*)&a3p[uu];
    ushort4 v0 = *(const ushort4*)&mub[(size_t)(uu + 0) * M];
    ushort4 v1 = *(const ushort4*)&mub[(size_t)(uu + 1) * M];
    ushort4 v2 = *(const ushort4*)&mub[(size_t)(uu + 2) * M];
    ushort4 v3 = *(const ushort4*)&mub[(size_t)(uu + 3) * M];
    float4 b0 = {bf2f(v0.x), bf2f(v0.y), bf2f(v0.z), bf2f(v0.w)};
    float4 b1 = {bf2f(v1.x), bf2f(v1.y), bf2f(v1.z), bf2f(v1.w)};
    float4 b2 = {bf2f(v2.x), bf2f(v2.y), bf2f(v2.z), bf2f(v2.w)};
    float4 b3 = {bf2f(v3.x), bf2f(v3.y), bf2f(v3.z), bf2f(v3.w)};
#define FMA4(ACC, AV) \
    ACC.x = fmaf(AV.x, b0.x, ACC.x); ACC.y = fmaf(AV.x, b0.y, ACC.y); \
    ACC.z = fmaf(AV.x, b0.z, ACC.z); ACC.w = fmaf(AV.x, b0.w, ACC.w); \
    ACC.x = fmaf(AV.y, b1.x, ACC.x); ACC.y = fmaf(AV.y, b1.y, ACC.y); \
    ACC.z = fmaf(AV.y, b1.z, ACC.z); ACC.w = fmaf(AV.y, b1.w, ACC.w); \
    ACC.x = fmaf(AV.z, b2.x, ACC.x); ACC.y = fmaf(AV.z, b2.y, ACC.y); \
    ACC.z = fmaf(AV.z, b2.z, ACC.z); ACC.w = fmaf(AV.z, b2.w, ACC.w); \
    ACC.x = fmaf(AV.w, b3.x, ACC.x); ACC.y = fmaf(AV.w, b3.y, ACC.y); \
    ACC.z = fmaf(AV.w, b3.z, ACC.z); ACC.w = fmaf(AV.w, b3.w, ACC.w);
    FMA4(acc0, a0) FMA4(acc1, a1) FMA4(acc2, a2) FMA4(acc3, a3)
#undef FMA4
  }
  float* cp = CsP + kc * 512 + cg * 4;
  *(float4*)&cp[0]   = acc0;
  *(float4*)&cp[128] = acc1;
  *(float4*)&cp[256] = acc2;
  *(float4*)&cp[384] = acc3;
  __syncthreads();
  {
    int j = t;                     // 512 entries exactly
    float s = 0.f;
#pragma unroll
    for (int s16 = 0; s16 < 16; s16++) s += CsP[s16 * 512 + j];
    As[j] = s;                     // Cred[4][128]
  }
  __syncthreads();
}

// epilogue matmul (1 row/thread): acc = Cred_row @ W3T-column (wcol pre-offset)
__device__ __forceinline__ float epi_mm1(const float* __restrict__ Cred,
                                         const float* __restrict__ wcol, int ra) {
  float acc = 0.f;
#pragma unroll 4
  for (int m = 0; m < 128; m += 4) {
    float4 c0 = *(const float4*)&Cred[ra * 128 + m];
    acc = fmaf(c0.x, wcol[(m + 0) * 128],
          fmaf(c0.y, wcol[(m + 1) * 128],
          fmaf(c0.z, wcol[(m + 2) * 128],
          fmaf(c0.w, wcol[(m + 3) * 128], acc))));
  }
  return acc;
}

// ================= fused A-iteration (it 0..2; z=0: A1, z=1: A2, z=2: B0 GEMM at it0) =================
__global__ __launch_bounds__(512) void k_iterA(
    const us16* __restrict__ PT1bf, const us16* __restrict__ PT2bf,
    const us16* __restrict__ cur1, const us16* __restrict__ cur2,
    const us16* __restrict__ curB0,
    us16* __restrict__ nxt1, us16* __restrict__ nxt2, float* __restrict__ CB0f,
    float* __restrict__ s1buf, float* __restrict__ s2buf,
    const float* __restrict__ wd1, const float* __restrict__ wd2,
    const float* __restrict__ dr, const float* __restrict__ ddep,
    const float* __restrict__ W3A1T, const float* __restrict__ W3A2T,
    const float* __restrict__ W3BT,
    const float* __restrict__ W4A1, const float* __restrict__ W4A2,
    const float* __restrict__ W5, const float* __restrict__ W6) {
  __shared__ float smem[12288];
  float* As = smem;
  float* CsP = smem + 4096;
  const int z = blockIdx.z;
  const int t = threadIdx.x, r0 = blockIdx.x * 4;
  const us16* PT = (z == 1) ? PT2bf : PT1bf;
  const us16* cur = (z == 0) ? cur1 : (z == 1) ? cur2 : curB0;

  gemm4_bf(PT, cur, As, CsP, r0, t);

  const float* W3T = (z == 0) ? W3A1T : (z == 1) ? W3A2T : W3BT;
  int col = t & 127, ra = t >> 7;     // 0..3
  int rA = r0 + ra;
  float acc = epi_mm1(As, W3T + (z < 2 ? 128 : 0) + col, ra);
  if (z == 2) {                       // B0 GEMM: store raw C (pre-bias, pre-relu)
    CB0f[(size_t)rA * M + col] = acc;
    return;
  }
  float* sbuf = z ? s2buf : s1buf;
  const float* wdv = z ? wd2 : wd1;
  const float* dist = z ? ddep : dr;
  const float* W4c = z ? W4A2 : W4A1;
  const float* Wg = z ? W6 : W5;
  us16* nxt = z ? nxt2 : nxt1;
  float w30 = W3T[col], w4 = W4c[col];
  float sv = wdv[rA] * fmaxf(sbuf[rA], 0.f);
  float o0 = fmaxf(fmaf(sv, w30, fmaf(dist[rA], w4, acc)), 0.f);
  nxt[(size_t)rA * M + col] = f2bf(o0);
  // producer-side s-dot for next iteration's epilogue
  __syncthreads();
  CsP[ra * 128 + col] = o0;
  __syncthreads();
  if (t < 64) {
    int row = t >> 4, l16 = t & 15;
    const float* cr = &CsP[row * 128 + l16 * 8];
    float4 x0 = *(const float4*)cr, x1 = *(const float4*)(cr + 4);
    float4 g0 = *(const float4*)(Wg + l16 * 8), g1 = *(const float4*)(Wg + l16 * 8 + 4);
    float sp = x0.x * g0.x + x0.y * g0.y + x0.z * g0.z + x0.w * g0.w
             + x1.x * g1.x + x1.y * g1.y + x1.z * g1.z + x1.w * g1.w;
#pragma unroll
    for (int o = 8; o; o >>= 1) sp += __shfl_xor(sp, o);
    if (l16 == 0) sbuf[r0 + row] = sp;
  }
}

// ================= A-it3 fused: both chains + bias + muB1 (bmerge folded in) =================
__global__ __launch_bounds__(512) void k_iterA3(
    const us16* __restrict__ PT1bf, const us16* __restrict__ PT2bf,
    const us16* __restrict__ curA1, const us16* __restrict__ curA2,
    us16* __restrict__ nxtA1, us16* __restrict__ nxtA2,
    const float* __restrict__ s1buf, const float* __restrict__ s2buf,
    const float* __restrict__ wd1, const float* __restrict__ wd2,
    const float* __restrict__ dr, const float* __restrict__ ddep,
    const float* __restrict__ W3A1T, const float* __restrict__ W3A2T,
    const float* __restrict__ W4A1, const float* __restrict__ W4A2,
    const float* __restrict__ W4BT, const float* __restrict__ CB0f,
    float* __restrict__ biasb, us16* __restrict__ muB1) {
  __shared__ float smem[12288 + 512];
  float* As = smem;
  float* CsP = smem + 4096;
  float* st1 = smem + 12288;          // chain-1 new mu f32 [4][128]
  const int t = threadIdx.x, r0 = blockIdx.x * 4;
  int col = t & 127, ra = t >> 7;
  int rA = r0 + ra;

  // ---- chain 1 (A1) ----
  gemm4_bf(PT1bf, curA1, As, CsP, r0, t);
  {
    float acc = epi_mm1(As, W3A1T + 128 + col, ra);
    float w30 = W3A1T[col], w4 = W4A1[col];
    float sv = wd1[rA] * fmaxf(s1buf[rA], 0.f);
    float o0 = fmaxf(fmaf(sv, w30, fmaf(dr[rA], w4, acc)), 0.f);
    nxtA1[(size_t)rA * M + col] = f2bf(o0);
    st1[ra * 128 + col] = o0;
  }
  __syncthreads();   // epi reads of As done before chain-2 staging overwrites

  // ---- chain 2 (A2) ----
  gemm4_bf(PT2bf, curA2, As, CsP, r0, t);
  {
    float acc = epi_mm1(As, W3A2T + 128 + col, ra);
    float w30 = W3A2T[col], w4 = W4A2[col];
    float sv = wd2[rA] * fmaxf(s2buf[rA], 0.f);
    float o0 = fmaxf(fmaf(sv, w30, fmaf(ddep[rA], w4, acc)), 0.f);
    nxtA2[(size_t)rA * M + col] = f2bf(o0);
    CsP[ra * 128 + col] = o0;          // stash chain-2 (CsP free after gemm4)
  }
  __syncthreads();

  // ---- bias = [A1new, A2new] @ W4B.T ; muB1 = relu(CB0 + bias) (block-local rows) ----
  float b0 = 0.f;
#pragma unroll 4
  for (int c = 0; c < 128; c += 4) {
    float4 s0 = *(const float4*)&st1[ra * 128 + c];
    float w0 = W4BT[(c + 0) * 128 + col], w1 = W4BT[(c + 1) * 128 + col];
    float w2 = W4BT[(c + 2) * 128 + col], w3 = W4BT[(c + 3) * 128 + col];
    b0 = fmaf(s0.x, w0, fmaf(s0.y, w1, fmaf(s0.z, w2, fmaf(s0.w, w3, b0))));
  }
#pragma unroll 4
  for (int c = 0; c < 128; c += 4) {
    float4 s0 = *(const float4*)&CsP[ra * 128 + c];
    float w0 = W4BT[(c + 128) * 128 + col], w1 = W4BT[(c + 129) * 128 + col];
    float w2 = W4BT[(c + 130) * 128 + col], w3 = W4BT[(c + 131) * 128 + col];
    b0 = fmaf(s0.x, w0, fmaf(s0.y, w1, fmaf(s0.z, w2, fmaf(s0.w, w3, b0))));
  }
  biasb[(size_t)rA * M + col] = b0;
  muB1[(size_t)rA * M + col] = f2bf(fmaxf(CB0f[(size_t)rA * M + col] + b0, 0.f));
}

// ================= fused B-iteration (B1..B3) =================
__global__ __launch_bounds__(512) void k_iterB(
    const us16* __restrict__ PT1bf, const us16* __restrict__ curbf,
    us16* __restrict__ nxtbf,
    const float* __restrict__ W3BT, const float* __restrict__ biasb,
    const float* __restrict__ W7, float* __restrict__ gsum,
    unsigned int* __restrict__ gcnt, float* __restrict__ out, int last) {
  __shared__ float smem[12288];
  __shared__ float redf[8];
  float* As = smem;
  float* CsP = smem + 4096;
  int t = threadIdx.x, r0 = blockIdx.x * 4;
  gemm4_bf(PT1bf, curbf, As, CsP, r0, t);
  int col = t & 127, ra = t >> 7;
  int rA = r0 + ra;
  float acc = epi_mm1(As, W3BT + col, ra);
  float o0 = fmaxf(acc + biasb[(size_t)rA * M + col], 0.f);
  if (!last) {
    nxtbf[(size_t)rA * M + col] = f2bf(o0);
  } else {
    float s = o0 * W7[col];
#pragma unroll
    for (int off = 32; off; off >>= 1) s += __shfl_xor(s, off);
    if ((t & 63) == 0) redf[t >> 6] = s;
    __syncthreads();
    if (t == 0) {
      float bs = redf[0] + redf[1] + redf[2] + redf[3]
               + redf[4] + redf[5] + redf[6] + redf[7];
      atomicAdd(gsum, bs);
      __threadfence();
      unsigned int old = atomicAdd(gcnt, 1u);
      if (old == 255u) {
        float tot = atomicAdd(gsum, 0.f);
        out[0] = fmaxf(tot, 0.f);
      }
    }
  }
}

extern "C" void kernel_launch(void* const* d_in, const int* in_sizes, int n_in,
                              void* d_out, int out_size, void* d_ws, size_t ws_size,
                              hipStream_t stream) {
  (void)in_sizes; (void)n_in; (void)out_size; (void)ws_size;
  const float* D     = (const float*)d_in[0];
  const float* dd    = (const float*)d_in[1];
  const float* dr    = (const float*)d_in[2];
  const float* ddep  = (const float*)d_in[3];
  const float* mu0A1 = (const float*)d_in[4];
  const float* mu0A2 = (const float*)d_in[5];
  const float* mu0B  = (const float*)d_in[6];
  const float* W1    = (const float*)d_in[7];
  const float* W2    = (const float*)d_in[8];
  const float* W3A1  = (const float*)d_in[9];
  const float* W3A2  = (const float*)d_in[10];
  const float* W4A1  = (const float*)d_in[11];
  const float* W4A2  = (const float*)d_in[12];
  const float* W3B   = (const float*)d_in[13];
  const float* W4B   = (const float*)d_in[14];
  const float* W5    = (const float*)d_in[15];
  const float* W6    = (const float*)d_in[16];
  const float* W7    = (const float*)d_in[17];

  float* wsf = (float*)d_ws;
  size_t o = 0;
  auto alloc = [&](size_t n) { float* p = wsf + o; o += n; return p; };
  us16* PT1bf   = (us16*)alloc((size_t)N * N / 2);
  us16* PT2bf   = (us16*)alloc((size_t)N * N / 2);
  float* W3A1T  = alloc(129 * 128);
  float* W3A2T  = alloc(129 * 128);
  float* W3BT   = alloc(128 * 128);
  float* W4BT   = alloc(256 * 128);
  float* s1     = alloc(N);
  float* s2     = alloc(N);
  float* wd1    = alloc(N);
  float* wd2    = alloc(N);
  us16* muA1_0  = (us16*)alloc((size_t)N * M / 2);
  us16* muA1_a  = (us16*)alloc((size_t)N * M / 2);
  us16* muA1_b  = (us16*)alloc((size_t)N * M / 2);
  us16* muA2_0  = (us16*)alloc((size_t)N * M / 2);
  us16* muA2_a  = (us16*)alloc((size_t)N * M / 2);
  us16* muA2_b  = (us16*)alloc((size_t)N * M / 2);
  us16* muB_0   = (us16*)alloc((size_t)N * M / 2);
  us16* muB_a   = (us16*)alloc((size_t)N * M / 2);
  us16* muB_b   = (us16*)alloc((size_t)N * M / 2);
  float* CB0f   = alloc((size_t)N * M);
  float* biasb  = alloc((size_t)N * M);
  float* gsum   = alloc(1);
  unsigned int* gcnt = (unsigned int*)alloc(1);

  // Stage 1: edge (direct-D) + all prep work in one launch
  k_edge_prep<<<1858, 256, 0, stream>>>(D, dd, W1, W2, PT1bf, PT2bf, wd1, wd2,
                                        W3A1, W3A2, W3B, W4B,
                                        W3A1T, W3A2T, W3BT, W4BT,
                                        mu0A1, mu0A2, mu0B, W5, W6, s1, s2,
                                        muA1_0, muA2_0, muB_0, gsum, gcnt);

  // Stages 2-4: A iterations 0..2 (it0 carries B0 GEMM as z=2)
  const us16* c1 = muA1_0;
  const us16* c2 = muA2_0;
  us16* b1[2] = {muA1_a, muA1_b};
  us16* b2[2] = {muA2_a, muA2_b};
  for (int it = 0; it < 3; it++) {
    dim3 grid(256, 1, it == 0 ? 3 : 2);
    k_iterA<<<grid, 512, 0, stream>>>(PT1bf, PT2bf, c1, c2, muB_0,
        b1[it & 1], b2[it & 1], CB0f, s1, s2, wd1, wd2, dr, ddep,
        W3A1T, W3A2T, W3BT, W4A1, W4A2, W5, W6);
    c1 = b1[it & 1];
    c2 = b2[it & 1];
  }

  // Stage 5: A it3 + bias + muB1 (bmerge fused)
  k_iterA3<<<256, 512, 0, stream>>>(PT1bf, PT2bf, c1, c2,
      muA1_b, muA2_b, s1, s2, wd1, wd2, dr, ddep,
      W3A1T, W3A2T, W4A1, W4A2, W4BT, CB0f, biasb, muB_a);

  // Stages 6-8: B1..B3
  const us16* cB = muB_a;
  us16* bB[2] = {muB_b, muB_a};
  for (int i = 0; i < 3; i++) {
    k_iterB<<<256, 512, 0, stream>>>(PT1bf, cB, bB[i & 1],
        W3BT, biasb, W7, gsum, gcnt, (float*)d_out, i == 2 ? 1 : 0);
    cB = bB[i & 1];
  }
}